// Round 17
// baseline (960.103 us; speedup 1.0000x reference)
//
#include <hip/hip_runtime.h>
#include <math.h>

#define NINT 871           // int(sqrt(3)*2*1.3/STEP) - 1
#define NB 256             // rays
#define NPTS (NB*NINT)     // 222976
#define NUM_EMB 512
#define EMB_DIM 64
#define RESO 64
#define STEP_F 0.005158730158730159f
#define RADIUS_F 1.3f
#define PCC_SC 24.615384615384617f   // RESO/(2*RADIUS)

// ws layout in floats (identical to the round-8/12/14 passing layout)
#define WS_RD    0         // 256*3
#define WS_TN    768       // 256
#define WS_SHM   1024      // 256*9
#define WS_E2    3328      // 512
#define WS_CNT   3840      // 512 (counts, zeroed each call)
#define WS_ELOSS 4352      // 1   (zeroed each call)
#define WS_RGBS  4608      // NPTS float4, ray-major: [ray][s]

__device__ __forceinline__ float wave_reduce_sum(float v) {
    #pragma unroll
    for (int off = 32; off > 0; off >>= 1) v += __shfl_down(v, off, 64);
    return v;
}

// ---------- Kernel A: per-ray setup + emb row norms ----------
__global__ void setup_kernel(const float* __restrict__ rays_o,
                             const float* __restrict__ rays_d,
                             const float* __restrict__ emb,
                             float* __restrict__ ws) {
    int gid = blockIdx.x * blockDim.x + threadIdx.x;
    if (gid < NB) {
        int r = gid;
        float dx = rays_d[r*3+0], dy = rays_d[r*3+1], dz = rays_d[r*3+2];
        float n = sqrtf(dx*dx + dy*dy + dz*dz);
        float rx = dx/n, ry = dy/n, rz = dz/n;
        ws[WS_RD + r*3+0] = rx; ws[WS_RD + r*3+1] = ry; ws[WS_RD + r*3+2] = rz;
        float ox = rays_o[r*3+0], oy = rays_o[r*3+1], oz = rays_o[r*3+2];
        float ivx = 1.0f/rx, ivy = 1.0f/ry, ivz = 1.0f/rz;
        float mnx = fminf((-RADIUS_F - ox)*ivx, (RADIUS_F - ox)*ivx);
        float mny = fminf((-RADIUS_F - oy)*ivy, (RADIUS_F - oy)*ivy);
        float mnz = fminf((-RADIUS_F - oz)*ivz, (RADIUS_F - oz)*ivz);
        float tn = fmaxf(fmaxf(fmaxf(mnx, mny), mnz), 0.0f);
        ws[WS_TN + r] = tn;
        const float C0=0.28209479177387814f, C1=0.4886025119029199f;
        const float C20=1.0925484305920792f, C22=0.31539156525252005f, C24=0.5462742152960396f;
        float x = rx, y = ry, z = rz;
        float sh[9];
        sh[0] = C0;
        sh[1] = -C1*y;
        sh[2] =  C1*z;
        sh[3] = -C1*x;
        sh[4] =  C20*x*y;
        sh[5] = -C20*y*z;
        sh[6] =  C22*(2.0f*z*z - x*x - y*y);
        sh[7] = -C20*x*z;
        sh[8] =  C24*(x*x - y*y);
        #pragma unroll
        for (int j = 0; j < 9; ++j) ws[WS_SHM + r*9 + j] = sh[j];
    }
    int e = gid - NB;
    if (e >= 0 && e < NUM_EMB) {
        float s = 0.0f;
        #pragma unroll 8
        for (int k = 0; k < EMB_DIM; ++k) { float v = emb[e*EMB_DIM + k]; s += v*v; }
        ws[WS_E2 + e] = s;
    }
}

// ---------- Kernel B: fused pipeline, 1 wave handles 128 samples (2/thread) ----------
// Round-14 structure with 2 points per thread: each broadcast ds_read of an
// emb chunk now feeds 8 FMAs (2 pts x 4 dims) instead of 4, and live waves
// halve -> chip-wide LDS-issue work (the round-14 floor) halves. cls rows
// stay persistent (emb tiles get their own region); per-point FMA order and
// ascending code comparisons unchanged -> identical argmin. MLP runs per
// point sequentially. No wave-indexed slicing (rounds 9/15 trap), no
// launch_bounds min-waves cap (rounds 4-6 trap).
__global__ __launch_bounds__(64) void point_kernel(
    const float* __restrict__ rays_o,
    const float* __restrict__ data,
    const float* __restrict__ emb,
    const float* __restrict__ W1, const float* __restrict__ b1,
    const float* __restrict__ W2, const float* __restrict__ b2,
    const float* __restrict__ W3, const float* __restrict__ b3,
    float* __restrict__ ws)
{
    __shared__ float cls[128*68];      // 34816 B, persistent through MLP
    __shared__ float lds_emb[32*64];   // 8192 B; hist overlays after VQ
    __shared__ float lds_e2[32];

    const int tid = threadIdx.x;   // 0..63
    const int ray = blockIdx.y;
    const int sA  = blockIdx.x * 128 + tid;
    const int sB  = sA + 64;
    const bool liveA = (sA < NINT);
    const bool liveB = (sB < NINT);
    const int ssA = liveA ? sA : (NINT - 1);
    const int ssB = liveB ? sB : (NINT - 1);

    // wave-uniform ray data
    const float rx = ws[WS_RD + ray*3+0];
    const float ry = ws[WS_RD + ray*3+1];
    const float rz = ws[WS_RD + ray*3+2];
    const float tn = ws[WS_TN + ray];
    const float ox = rays_o[ray*3+0], oy = rays_o[ray*3+1], oz = rays_o[ray*3+2];

    const float tA = tn + STEP_F * (float)ssA;
    const float tB = tn + STEP_F * (float)ssB;
    const float pxA = ox + tA*rx, pyA = oy + tA*ry, pzA = oz + tA*rz;
    const float pxB = ox + tB*rx, pyB = oy + tB*ry, pzB = oz + tB*rz;
    const bool maskA = liveA && (fabsf(pxA) < RADIUS_F) && (fabsf(pyA) < RADIUS_F) && (fabsf(pzA) < RADIUS_F);
    const bool maskB = liveB && (fabsf(pxB) < RADIUS_F) && (fabsf(pyB) < RADIUS_F) && (fabsf(pzB) < RADIUS_F);

    // ---- dead-wave early exit ----
    unsigned long long alive = __ballot(maskA || maskB);
    if (alive == 0ull) {
        float4 z4; z4.x = 0.0f; z4.y = 0.0f; z4.z = 0.0f; z4.w = 0.0f;
        if (liveA) ((float4*)(ws + WS_RGBS))[ray*NINT + sA] = z4;
        if (liveB) ((float4*)(ws + WS_RGBS))[ray*NINT + sB] = z4;
        return;
    }

    // trilinear coords A
    float ixA = fminf(fmaxf((pxA/RADIUS_F + 1.0f)*0.5f*63.0f, 0.0f), 63.0f);
    float iyA = fminf(fmaxf((pyA/RADIUS_F + 1.0f)*0.5f*63.0f, 0.0f), 63.0f);
    float izA = fminf(fmaxf((pzA/RADIUS_F + 1.0f)*0.5f*63.0f, 0.0f), 63.0f);
    int x0A = (int)floorf(ixA); float wxA = ixA - (float)x0A; int x1A = x0A+1 > 63 ? 63 : x0A+1;
    int y0A = (int)floorf(iyA); float wyA = iyA - (float)y0A; int y1A = y0A+1 > 63 ? 63 : y0A+1;
    int z0A = (int)floorf(izA); float wzA = izA - (float)z0A; int z1A = z0A+1 > 63 ? 63 : z0A+1;
    const int b000A = z0A*4096 + y0A*64 + x0A;
    const int dxoA = x1A - x0A;
    const int dyoA = (y1A - y0A)*64;
    const int dzoA = (z1A - z0A)*4096;
    const float omwxA = 1.0f-wxA, omwyA = 1.0f-wyA, omwzA = 1.0f-wzA;

    // trilinear coords B
    float ixB = fminf(fmaxf((pxB/RADIUS_F + 1.0f)*0.5f*63.0f, 0.0f), 63.0f);
    float iyB = fminf(fmaxf((pyB/RADIUS_F + 1.0f)*0.5f*63.0f, 0.0f), 63.0f);
    float izB = fminf(fmaxf((pzB/RADIUS_F + 1.0f)*0.5f*63.0f, 0.0f), 63.0f);
    int x0B = (int)floorf(ixB); float wxB = ixB - (float)x0B; int x1B = x0B+1 > 63 ? 63 : x0B+1;
    int y0B = (int)floorf(iyB); float wyB = iyB - (float)y0B; int y1B = y0B+1 > 63 ? 63 : y0B+1;
    int z0B = (int)floorf(izB); float wzB = izB - (float)z0B; int z1B = z0B+1 > 63 ? 63 : z0B+1;
    const int b000B = z0B*4096 + y0B*64 + x0B;
    const int dxoB = x1B - x0B;
    const int dyoB = (y1B - y0B)*64;
    const int dzoB = (z1B - z0B)*4096;
    const float omwxB = 1.0f-wxB, omwyB = 1.0f-wyB, omwzB = 1.0f-wzB;

    // ---- interp: rolled loop, both points, retire to LDS ----
    float* rowA = cls + tid*68;
    float* rowB = cls + (64 + tid)*68;
    #pragma unroll 4
    for (int c = 0; c < EMB_DIM; ++c) {
        {
            const float* dc = data + c*262144 + b000A;
            float v000 = dc[0],         v001 = dc[dxoA];
            float v010 = dc[dyoA],      v011 = dc[dyoA+dxoA];
            float v100 = dc[dzoA],      v101 = dc[dzoA+dxoA];
            float v110 = dc[dzoA+dyoA], v111 = dc[dzoA+dyoA+dxoA];
            float c00 = v000*omwxA + v001*wxA;
            float c01 = v010*omwxA + v011*wxA;
            float c10 = v100*omwxA + v101*wxA;
            float c11 = v110*omwxA + v111*wxA;
            rowA[c] = (c00*omwyA + c01*wyA)*omwzA + (c10*omwyA + c11*wyA)*wzA;
        }
        {
            const float* dc = data + c*262144 + b000B;
            float v000 = dc[0],         v001 = dc[dxoB];
            float v010 = dc[dyoB],      v011 = dc[dyoB+dxoB];
            float v100 = dc[dzoB],      v101 = dc[dzoB+dxoB];
            float v110 = dc[dzoB+dyoB], v111 = dc[dzoB+dyoB+dxoB];
            float c00 = v000*omwxB + v001*wxB;
            float c01 = v010*omwxB + v011*wxB;
            float c10 = v100*omwxB + v101*wxB;
            float c11 = v110*omwxB + v111*wxB;
            rowB[c] = (c00*omwyB + c01*wyB)*omwzB + (c10*omwyB + c11*wyB)*wzB;
        }
    }
    __syncthreads();

    // ---- rehydrate both coarse arrays into registers ----
    float cA[EMB_DIM], cB[EMB_DIM];
    #pragma unroll
    for (int k4 = 0; k4 < 16; ++k4) {
        float4 va = *(const float4*)(rowA + k4*4);
        cA[k4*4+0] = va.x; cA[k4*4+1] = va.y; cA[k4*4+2] = va.z; cA[k4*4+3] = va.w;
        float4 vb = *(const float4*)(rowB + k4*4);
        cB[k4*4+0] = vb.x; cB[k4*4+1] = vb.y; cB[k4*4+2] = vb.z; cB[k4*4+3] = vb.w;
    }

    // ---- VQ argmin over 512 codes; emb staged in 16 x 32-code LDS tiles ----
    float bestA = 3.4e38f, bestB = 3.4e38f; int bcA = 0, bcB = 0;
    for (int tile = 0; tile < 16; ++tile) {
        const int cbase = tile*32;
        {
            const float4* src = (const float4*)(emb + cbase*EMB_DIM);
            float4* dst = (float4*)lds_emb;
            #pragma unroll
            for (int i = 0; i < 8; ++i) dst[tid + i*64] = src[tid + i*64];
            if (tid < 32) lds_e2[tid] = ws[WS_E2 + cbase + tid];
        }
        __syncthreads();

        for (int cq = 0; cq < 8; ++cq) {
            const float* e0 = lds_emb + cq*256;
            float dA0 = 0.0f, dA1 = 0.0f, dA2 = 0.0f, dA3 = 0.0f;
            float dB0 = 0.0f, dB1 = 0.0f, dB2 = 0.0f, dB3 = 0.0f;
            #pragma unroll
            for (int k4 = 0; k4 < 16; ++k4) {
                float4 e0v = *(const float4*)(e0 + k4*4);
                float4 e1v = *(const float4*)(e0 + 64 + k4*4);
                float4 e2v = *(const float4*)(e0 + 128 + k4*4);
                float4 e3v = *(const float4*)(e0 + 192 + k4*4);
                float a0 = cA[4*k4+0], a1 = cA[4*k4+1], a2 = cA[4*k4+2], a3 = cA[4*k4+3];
                float b0 = cB[4*k4+0], b1v = cB[4*k4+1], b2v = cB[4*k4+2], b3v = cB[4*k4+3];
                dA0 = fmaf(a0, e0v.x, dA0); dA0 = fmaf(a1, e0v.y, dA0);
                dA0 = fmaf(a2, e0v.z, dA0); dA0 = fmaf(a3, e0v.w, dA0);
                dA1 = fmaf(a0, e1v.x, dA1); dA1 = fmaf(a1, e1v.y, dA1);
                dA1 = fmaf(a2, e1v.z, dA1); dA1 = fmaf(a3, e1v.w, dA1);
                dA2 = fmaf(a0, e2v.x, dA2); dA2 = fmaf(a1, e2v.y, dA2);
                dA2 = fmaf(a2, e2v.z, dA2); dA2 = fmaf(a3, e2v.w, dA2);
                dA3 = fmaf(a0, e3v.x, dA3); dA3 = fmaf(a1, e3v.y, dA3);
                dA3 = fmaf(a2, e3v.z, dA3); dA3 = fmaf(a3, e3v.w, dA3);
                dB0 = fmaf(b0, e0v.x, dB0); dB0 = fmaf(b1v, e0v.y, dB0);
                dB0 = fmaf(b2v, e0v.z, dB0); dB0 = fmaf(b3v, e0v.w, dB0);
                dB1 = fmaf(b0, e1v.x, dB1); dB1 = fmaf(b1v, e1v.y, dB1);
                dB1 = fmaf(b2v, e1v.z, dB1); dB1 = fmaf(b3v, e1v.w, dB1);
                dB2 = fmaf(b0, e2v.x, dB2); dB2 = fmaf(b1v, e2v.y, dB2);
                dB2 = fmaf(b2v, e2v.z, dB2); dB2 = fmaf(b3v, e2v.w, dB2);
                dB3 = fmaf(b0, e3v.x, dB3); dB3 = fmaf(b1v, e3v.y, dB3);
                dB3 = fmaf(b2v, e3v.z, dB3); dB3 = fmaf(b3v, e3v.w, dB3);
            }
            float q0 = lds_e2[cq*4+0], q1 = lds_e2[cq*4+1];
            float q2 = lds_e2[cq*4+2], q3 = lds_e2[cq*4+3];
            int cb = cbase + cq*4;
            float sA0 = q0 - 2.0f*dA0, sA1 = q1 - 2.0f*dA1;
            float sA2 = q2 - 2.0f*dA2, sA3 = q3 - 2.0f*dA3;
            if (sA0 < bestA) { bestA = sA0; bcA = cb + 0; }
            if (sA1 < bestA) { bestA = sA1; bcA = cb + 1; }
            if (sA2 < bestA) { bestA = sA2; bcA = cb + 2; }
            if (sA3 < bestA) { bestA = sA3; bcA = cb + 3; }
            float sB0 = q0 - 2.0f*dB0, sB1 = q1 - 2.0f*dB1;
            float sB2 = q2 - 2.0f*dB2, sB3 = q3 - 2.0f*dB3;
            if (sB0 < bestB) { bestB = sB0; bcB = cb + 0; }
            if (sB1 < bestB) { bestB = sB1; bcB = cb + 1; }
            if (sB2 < bestB) { bestB = sB2; bcB = cb + 2; }
            if (sB3 < bestB) { bestB = sB3; bcB = cb + 3; }
        }
        __syncthreads();
    }

    // ---- privatized counts histogram (lds_emb region now dead) ----
    {
        float* hist = lds_emb;   // 512 bins
        #pragma unroll
        for (int i = 0; i < 8; ++i) hist[tid + i*64] = 0.0f;
        __syncthreads();
        if (maskA) atomicAdd(&hist[bcA], 1.0f);
        if (maskB) atomicAdd(&hist[bcB], 1.0f);
        __syncthreads();
        #pragma unroll
        for (int i = 0; i < 8; ++i) {
            float h = hist[tid + i*64];
            if (h != 0.0f) atomicAdd(&ws[WS_CNT + tid + i*64], h);
        }
    }

    float shm_[9];
    #pragma unroll
    for (int j = 0; j < 9; ++j) shm_[j] = ws[WS_SHM + ray*9 + j];

    // ================= MLP for point A =================
    {
        float h1[32];
        #pragma unroll
        for (int j = 0; j < 32; ++j) h1[j] = b1[j];

        float diff2 = 0.0f;
        {
            const float4* eq4 = (const float4*)(emb + bcA*EMB_DIM);
            #pragma unroll
            for (int k4 = 0; k4 < 16; ++k4) {
                float4 q4 = eq4[k4];
                float q[4] = {q4.x, q4.y, q4.z, q4.w};
                #pragma unroll
                for (int u = 0; u < 4; ++u) {
                    int k = k4*4 + u;
                    float d  = q[u] - cA[k];
                    diff2 += d*d;
                    float xv = cA[k] + d;
                    #pragma unroll
                    for (int j = 0; j < 32; ++j) h1[j] = fmaf(xv, W1[k*32 + j], h1[j]);
                }
            }
        }
        float el = maskA ? diff2 : 0.0f;
        el = wave_reduce_sum(el);
        if (tid == 0 && el != 0.0f) atomicAdd(&ws[WS_ELOSS], el);

        {
            float fx = pxA*PCC_SC + 32.0f; fx = (fx - floorf(fx))*2.0f - 1.0f;
            float fy = pyA*PCC_SC + 32.0f; fy = (fy - floorf(fy))*2.0f - 1.0f;
            float fz = pzA*PCC_SC + 32.0f; fz = (fz - floorf(fz))*2.0f - 1.0f;
            float fv[3] = {fx, fy, fz};
            float dv[3] = {rx, ry, rz};
            #pragma unroll
            for (int a = 0; a < 3; ++a) {
                #pragma unroll
                for (int f = 0; f < 4; ++f) {
                    float angf = fv[a] * (float)(1 << f);
                    float angd = dv[a] * (float)(1 << f);
                    float sf = sinf(angf), cf = cosf(angf);
                    float sd = sinf(angd), cd = cosf(angd);
                    int rowS = 64 + a*8 + f;
                    int rowC = rowS + 4;
                    int rowSD = 88 + a*8 + f;
                    int rowCD = rowSD + 4;
                    #pragma unroll
                    for (int j = 0; j < 32; ++j) {
                        h1[j] = fmaf(sf, W1[rowS*32 + j], h1[j]);
                        h1[j] = fmaf(cf, W1[rowC*32 + j], h1[j]);
                        h1[j] = fmaf(sd, W1[rowSD*32 + j], h1[j]);
                        h1[j] = fmaf(cd, W1[rowCD*32 + j], h1[j]);
                    }
                }
            }
        }
        #pragma unroll
        for (int j = 0; j < 32; ++j) h1[j] = fmaxf(h1[j], 0.0f);

        float h2[32];
        #pragma unroll
        for (int j = 0; j < 32; ++j) h2[j] = b2[j];
        #pragma unroll
        for (int k = 0; k < 32; ++k) {
            float hv = h1[k];
            #pragma unroll
            for (int j = 0; j < 32; ++j) h2[j] = fmaf(hv, W2[k*32 + j], h2[j]);
        }
        #pragma unroll
        for (int j = 0; j < 32; ++j) h2[j] = fmaxf(h2[j], 0.0f);

        float shd[28];
        #pragma unroll
        for (int j = 0; j < 28; ++j) shd[j] = b3[j];
        #pragma unroll
        for (int k = 0; k < 32; ++k) {
            float hv = h2[k];
            #pragma unroll
            for (int j = 0; j < 28; ++j) shd[j] = fmaf(hv, W3[k*28 + j], shd[j]);
        }

        const float mf = maskA ? 1.0f : 0.0f;
        float sigma = fmaxf(shd[27], 0.0f) * mf;
        float rgb[3];
        #pragma unroll
        for (int c = 0; c < 3; ++c) {
            float acc = 0.0f;
            #pragma unroll
            for (int j = 0; j < 9; ++j) acc = fmaf(shm_[j], shd[c*9 + j], acc);
            rgb[c] = fminf(fmaxf(acc*mf + 0.5f, 0.0f), 1.0f);
        }
        if (liveA) {
            float4 o4; o4.x = rgb[0]; o4.y = rgb[1]; o4.z = rgb[2]; o4.w = sigma;
            ((float4*)(ws + WS_RGBS))[ray*NINT + sA] = o4;
        }
    }

    // ================= MLP for point B =================
    {
        float h1[32];
        #pragma unroll
        for (int j = 0; j < 32; ++j) h1[j] = b1[j];

        float diff2 = 0.0f;
        {
            const float4* eq4 = (const float4*)(emb + bcB*EMB_DIM);
            #pragma unroll
            for (int k4 = 0; k4 < 16; ++k4) {
                float4 q4 = eq4[k4];
                float q[4] = {q4.x, q4.y, q4.z, q4.w};
                #pragma unroll
                for (int u = 0; u < 4; ++u) {
                    int k = k4*4 + u;
                    float d  = q[u] - cB[k];
                    diff2 += d*d;
                    float xv = cB[k] + d;
                    #pragma unroll
                    for (int j = 0; j < 32; ++j) h1[j] = fmaf(xv, W1[k*32 + j], h1[j]);
                }
            }
        }
        float el = maskB ? diff2 : 0.0f;
        el = wave_reduce_sum(el);
        if (tid == 0 && el != 0.0f) atomicAdd(&ws[WS_ELOSS], el);

        {
            float fx = pxB*PCC_SC + 32.0f; fx = (fx - floorf(fx))*2.0f - 1.0f;
            float fy = pyB*PCC_SC + 32.0f; fy = (fy - floorf(fy))*2.0f - 1.0f;
            float fz = pzB*PCC_SC + 32.0f; fz = (fz - floorf(fz))*2.0f - 1.0f;
            float fv[3] = {fx, fy, fz};
            float dv[3] = {rx, ry, rz};
            #pragma unroll
            for (int a = 0; a < 3; ++a) {
                #pragma unroll
                for (int f = 0; f < 4; ++f) {
                    float angf = fv[a] * (float)(1 << f);
                    float angd = dv[a] * (float)(1 << f);
                    float sf = sinf(angf), cf = cosf(angf);
                    float sd = sinf(angd), cd = cosf(angd);
                    int rowS = 64 + a*8 + f;
                    int rowC = rowS + 4;
                    int rowSD = 88 + a*8 + f;
                    int rowCD = rowSD + 4;
                    #pragma unroll
                    for (int j = 0; j < 32; ++j) {
                        h1[j] = fmaf(sf, W1[rowS*32 + j], h1[j]);
                        h1[j] = fmaf(cf, W1[rowC*32 + j], h1[j]);
                        h1[j] = fmaf(sd, W1[rowSD*32 + j], h1[j]);
                        h1[j] = fmaf(cd, W1[rowCD*32 + j], h1[j]);
                    }
                }
            }
        }
        #pragma unroll
        for (int j = 0; j < 32; ++j) h1[j] = fmaxf(h1[j], 0.0f);

        float h2[32];
        #pragma unroll
        for (int j = 0; j < 32; ++j) h2[j] = b2[j];
        #pragma unroll
        for (int k = 0; k < 32; ++k) {
            float hv = h1[k];
            #pragma unroll
            for (int j = 0; j < 32; ++j) h2[j] = fmaf(hv, W2[k*32 + j], h2[j]);
        }
        #pragma unroll
        for (int j = 0; j < 32; ++j) h2[j] = fmaxf(h2[j], 0.0f);

        float shd[28];
        #pragma unroll
        for (int j = 0; j < 28; ++j) shd[j] = b3[j];
        #pragma unroll
        for (int k = 0; k < 32; ++k) {
            float hv = h2[k];
            #pragma unroll
            for (int j = 0; j < 28; ++j) shd[j] = fmaf(hv, W3[k*28 + j], shd[j]);
        }

        const float mf = maskB ? 1.0f : 0.0f;
        float sigma = fmaxf(shd[27], 0.0f) * mf;
        float rgb[3];
        #pragma unroll
        for (int c = 0; c < 3; ++c) {
            float acc = 0.0f;
            #pragma unroll
            for (int j = 0; j < 9; ++j) acc = fmaf(shm_[j], shd[c*9 + j], acc);
            rgb[c] = fminf(fmaxf(acc*mf + 0.5f, 0.0f), 1.0f);
        }
        if (liveB) {
            float4 o4; o4.x = rgb[0]; o4.y = rgb[1]; o4.z = rgb[2]; o4.w = sigma;
            ((float4*)(ws + WS_RGBS))[ray*NINT + sB] = o4;
        }
    }
}

// ---------- Kernel C: per-ray compositing, one wave per ray ----------
__global__ void composite_kernel(const float* __restrict__ ws, float* __restrict__ out) {
    const int lane = threadIdx.x & 63;
    const int wid  = threadIdx.x >> 6;
    const int r = blockIdx.x * (blockDim.x >> 6) + wid;
    if (r >= NB) return;

    const float tn = ws[WS_TN + r];
    const float4* rs = ((const float4*)(ws + WS_RGBS)) + r*NINT;

    const int s0 = lane * 14;
    float T = 1.0f, c0 = 0.0f, c1 = 0.0f, c2 = 0.0f, dep = 0.0f, wsum = 0.0f;
    #pragma unroll 2
    for (int i = 0; i < 14; ++i) {
        int s = s0 + i;
        if (s < NINT) {
            float4 v = rs[s];
            float alpha = 1.0f - expf(-v.w * STEP_F);
            float w = alpha * T;
            c0 += w * v.x; c1 += w * v.y; c2 += w * v.z;
            dep  += w * (tn + STEP_F * (float)s);
            wsum += w;
            T *= (1.0f - alpha + 1e-10f);
        }
    }

    float inc = T;
    #pragma unroll
    for (int off = 1; off < 64; off <<= 1) {
        float o = __shfl_up(inc, off, 64);
        if (lane >= off) inc *= o;
    }
    float excl = __shfl_up(inc, 1, 64);
    if (lane == 0) excl = 1.0f;

    c0 *= excl; c1 *= excl; c2 *= excl; dep *= excl; wsum *= excl;
    c0 = wave_reduce_sum(c0);
    c1 = wave_reduce_sum(c1);
    c2 = wave_reduce_sum(c2);
    dep = wave_reduce_sum(dep);
    wsum = wave_reduce_sum(wsum);

    if (lane == 0) {
        float bg = 1.0f - wsum;
        out[r*3+0] = c0 + bg;
        out[r*3+1] = c1 + bg;
        out[r*3+2] = c2 + bg;
        out[768 + r] = dep;
    }
}

// ---------- Kernel D: loss + perplexity ----------
__global__ void finalize_kernel(const float* __restrict__ ws, float* __restrict__ out) {
    __shared__ float red[512];
    int t = threadIdx.x;
    float c = ws[WS_CNT + t];
    red[t] = c;
    __syncthreads();
    #pragma unroll
    for (int off = 256; off > 0; off >>= 1) {
        if (t < off) red[t] += red[t + off];
        __syncthreads();
    }
    float cnt = fmaxf(red[0], 1.0f);
    __syncthreads();
    float avg = c / cnt;
    red[t] = avg * logf(avg + 1e-10f);
    __syncthreads();
    #pragma unroll
    for (int off = 256; off > 0; off >>= 1) {
        if (t < off) red[t] += red[t + off];
        __syncthreads();
    }
    if (t == 0) {
        out[1024] = 0.25f * ws[WS_ELOSS] / (cnt * 64.0f);
        out[1025] = expf(-red[0]);
    }
}

extern "C" void kernel_launch(void* const* d_in, const int* in_sizes, int n_in,
                              void* d_out, int out_size, void* d_ws, size_t ws_size,
                              hipStream_t stream) {
    const float* rays_o = (const float*)d_in[0];
    const float* rays_d = (const float*)d_in[1];
    // d_in[2] = grid_id (int, unused)
    const float* data   = (const float*)d_in[3];
    const float* emb    = (const float*)d_in[4];
    const float* W1 = (const float*)d_in[5];
    const float* b1 = (const float*)d_in[6];
    const float* W2 = (const float*)d_in[7];
    const float* b2 = (const float*)d_in[8];
    const float* W3 = (const float*)d_in[9];
    const float* b3 = (const float*)d_in[10];
    float* ws  = (float*)d_ws;
    float* out = (float*)d_out;

    // zero the atomic accumulators (counts + eloss) every call
    hipMemsetAsync(ws + WS_CNT, 0, (NUM_EMB + 1) * sizeof(float), stream);

    setup_kernel<<<3, 256, 0, stream>>>(rays_o, rays_d, emb, ws);

    dim3 gB((NINT + 127) / 128, NB);   // 7 x 256 blocks, 64 threads, 2 samples/thread
    point_kernel<<<gB, 64, 0, stream>>>(rays_o, data, emb, W1, b1, W2, b2, W3, b3, ws);

    composite_kernel<<<64, 256, 0, stream>>>(ws, out);
    finalize_kernel<<<1, 512, 0, stream>>>(ws, out);
}

// Round 18
// 384.859 us; speedup vs baseline: 2.4947x; 2.4947x over previous
//
#include <hip/hip_runtime.h>
#include <math.h>

#define NINT 871           // int(sqrt(3)*2*1.3/STEP) - 1
#define NB 256             // rays
#define NPTS (NB*NINT)     // 222976
#define NUM_EMB 512
#define EMB_DIM 64
#define RESO 64
#define STEP_F 0.005158730158730159f
#define RADIUS_F 1.3f
#define PCC_SC 24.615384615384617f   // RESO/(2*RADIUS)

// ws layout in floats (identical to the round-8/12/14 passing layout)
#define WS_RD    0         // 256*3
#define WS_TN    768       // 256
#define WS_SHM   1024      // 256*9
#define WS_E2    3328      // 512
#define WS_CNT   3840      // 512 (counts, zeroed each call)
#define WS_ELOSS 4352      // 1   (zeroed each call)
#define WS_RGBS  4608      // NPTS float4, ray-major: [ray][s]

__device__ __forceinline__ float wave_reduce_sum(float v) {
    #pragma unroll
    for (int off = 32; off > 0; off >>= 1) v += __shfl_down(v, off, 64);
    return v;
}

// ---------- Kernel A: per-ray setup + emb row norms ----------
__global__ void setup_kernel(const float* __restrict__ rays_o,
                             const float* __restrict__ rays_d,
                             const float* __restrict__ emb,
                             float* __restrict__ ws) {
    int gid = blockIdx.x * blockDim.x + threadIdx.x;
    if (gid < NB) {
        int r = gid;
        float dx = rays_d[r*3+0], dy = rays_d[r*3+1], dz = rays_d[r*3+2];
        float n = sqrtf(dx*dx + dy*dy + dz*dz);
        float rx = dx/n, ry = dy/n, rz = dz/n;
        ws[WS_RD + r*3+0] = rx; ws[WS_RD + r*3+1] = ry; ws[WS_RD + r*3+2] = rz;
        float ox = rays_o[r*3+0], oy = rays_o[r*3+1], oz = rays_o[r*3+2];
        float ivx = 1.0f/rx, ivy = 1.0f/ry, ivz = 1.0f/rz;
        float mnx = fminf((-RADIUS_F - ox)*ivx, (RADIUS_F - ox)*ivx);
        float mny = fminf((-RADIUS_F - oy)*ivy, (RADIUS_F - oy)*ivy);
        float mnz = fminf((-RADIUS_F - oz)*ivz, (RADIUS_F - oz)*ivz);
        float tn = fmaxf(fmaxf(fmaxf(mnx, mny), mnz), 0.0f);
        ws[WS_TN + r] = tn;
        const float C0=0.28209479177387814f, C1=0.4886025119029199f;
        const float C20=1.0925484305920792f, C22=0.31539156525252005f, C24=0.5462742152960396f;
        float x = rx, y = ry, z = rz;
        float sh[9];
        sh[0] = C0;
        sh[1] = -C1*y;
        sh[2] =  C1*z;
        sh[3] = -C1*x;
        sh[4] =  C20*x*y;
        sh[5] = -C20*y*z;
        sh[6] =  C22*(2.0f*z*z - x*x - y*y);
        sh[7] = -C20*x*z;
        sh[8] =  C24*(x*x - y*y);
        #pragma unroll
        for (int j = 0; j < 9; ++j) ws[WS_SHM + r*9 + j] = sh[j];
    }
    int e = gid - NB;
    if (e >= 0 && e < NUM_EMB) {
        float s = 0.0f;
        #pragma unroll 8
        for (int k = 0; k < EMB_DIM; ++k) { float v = emb[e*EMB_DIM + k]; s += v*v; }
        ws[WS_E2 + e] = s;
    }
}

// ---------- Kernel B: fused per-point pipeline, one wave per block ----------
// Round-14 structure (best verified: 387 us total). Interp streams channels
// to a private LDS row (rolled loop, tiny live set), one static b128 pass
// rehydrates coarse[64] to registers, VQ scans emb from 8 x 64-code LDS
// tiles (broadcast ds_read), counts go through a privatized LDS histogram
// (one global atomic per nonzero bin per block).
__global__ __launch_bounds__(64) void point_kernel(
    const float* __restrict__ rays_o,
    const float* __restrict__ data,
    const float* __restrict__ emb,
    const float* __restrict__ W1, const float* __restrict__ b1,
    const float* __restrict__ W2, const float* __restrict__ b2,
    const float* __restrict__ W3, const float* __restrict__ b3,
    float* __restrict__ ws)
{
    __shared__ float smem[64*68];   // cls rows; emb tile overlay; then 512-bin hist
    __shared__ float lds_e2[64];

    const int tid = threadIdx.x;   // 0..63
    const int ray = blockIdx.y;
    const int s   = blockIdx.x * 64 + tid;
    const bool live = (s < NINT);
    const int  ss = live ? s : (NINT - 1);

    // wave-uniform ray data
    const float rx = ws[WS_RD + ray*3+0];
    const float ry = ws[WS_RD + ray*3+1];
    const float rz = ws[WS_RD + ray*3+2];
    const float tn = ws[WS_TN + ray];
    const float ox = rays_o[ray*3+0], oy = rays_o[ray*3+1], oz = rays_o[ray*3+2];

    const float t  = tn + STEP_F * (float)ss;
    const float px = ox + t*rx, py = oy + t*ry, pz = oz + t*rz;
    const bool mask = live && (fabsf(px) < RADIUS_F) && (fabsf(py) < RADIUS_F) && (fabsf(pz) < RADIUS_F);

    // ---- dead-wave early exit ----
    unsigned long long alive = __ballot(mask);
    if (alive == 0ull) {
        if (live) {
            float4 z4; z4.x = 0.0f; z4.y = 0.0f; z4.z = 0.0f; z4.w = 0.0f;
            ((float4*)(ws + WS_RGBS))[ray*NINT + s] = z4;
        }
        return;
    }

    // trilinear coords
    float ix = fminf(fmaxf((px/RADIUS_F + 1.0f)*0.5f*63.0f, 0.0f), 63.0f);
    float iy = fminf(fmaxf((py/RADIUS_F + 1.0f)*0.5f*63.0f, 0.0f), 63.0f);
    float iz = fminf(fmaxf((pz/RADIUS_F + 1.0f)*0.5f*63.0f, 0.0f), 63.0f);
    int x0 = (int)floorf(ix); float wx = ix - (float)x0; int x1 = x0+1 > 63 ? 63 : x0+1;
    int y0 = (int)floorf(iy); float wy = iy - (float)y0; int y1 = y0+1 > 63 ? 63 : y0+1;
    int z0 = (int)floorf(iz); float wz = iz - (float)z0; int z1 = z0+1 > 63 ? 63 : z0+1;
    const int b000 = z0*4096 + y0*64 + x0;
    const int dxo = x1 - x0;
    const int dyo = (y1 - y0)*64;
    const int dzo = (z1 - z0)*4096;
    const float omwx = 1.0f-wx, omwy = 1.0f-wy, omwz = 1.0f-wz;

    // ---- interp: ROLLED loop, each channel retires to LDS ----
    float* myrow = smem + tid*68;
    #pragma unroll 4
    for (int c = 0; c < EMB_DIM; ++c) {
        const float* dc = data + c*262144 + b000;
        float v000 = dc[0],       v001 = dc[dxo];
        float v010 = dc[dyo],     v011 = dc[dyo+dxo];
        float v100 = dc[dzo],     v101 = dc[dzo+dxo];
        float v110 = dc[dzo+dyo], v111 = dc[dzo+dyo+dxo];
        float c00 = v000*omwx + v001*wx;
        float c01 = v010*omwx + v011*wx;
        float c10 = v100*omwx + v101*wx;
        float c11 = v110*omwx + v111*wx;
        myrow[c] = (c00*omwy + c01*wy)*omwz + (c10*omwy + c11*wy)*wz;
    }
    __syncthreads();

    // ---- rehydrate coarse[64] into registers (16 static b128 reads) ----
    float coarse[EMB_DIM];
    #pragma unroll
    for (int k4 = 0; k4 < 16; ++k4) {
        float4 v = *(const float4*)(myrow + k4*4);
        coarse[k4*4+0] = v.x; coarse[k4*4+1] = v.y;
        coarse[k4*4+2] = v.z; coarse[k4*4+3] = v.w;
    }
    __syncthreads();   // cls now dead; safe to overlay emb tiles

    // ---- VQ argmin over 512 codes; emb staged in 8 x 64-code LDS tiles ----
    float best = 3.4e38f; int bc = 0;
    for (int tile = 0; tile < 8; ++tile) {
        const int cbase = tile*64;
        {
            const float4* src = (const float4*)(emb + cbase*EMB_DIM);
            float4* dst = (float4*)smem;
            #pragma unroll
            for (int i = 0; i < 16; ++i) dst[tid + i*64] = src[tid + i*64];
            lds_e2[tid] = ws[WS_E2 + cbase + tid];
        }
        __syncthreads();

        for (int cq = 0; cq < 16; ++cq) {
            const float* e0 = smem + cq*256;
            float d0 = 0.0f, d1 = 0.0f, d2 = 0.0f, d3 = 0.0f;
            #pragma unroll
            for (int k4 = 0; k4 < 16; ++k4) {
                float4 e0v = *(const float4*)(e0 + k4*4);
                float4 e1v = *(const float4*)(e0 + 64 + k4*4);
                float4 e2v = *(const float4*)(e0 + 128 + k4*4);
                float4 e3v = *(const float4*)(e0 + 192 + k4*4);
                float c0v = coarse[4*k4+0], c1v = coarse[4*k4+1];
                float c2v = coarse[4*k4+2], c3v = coarse[4*k4+3];
                d0 = fmaf(c0v, e0v.x, d0); d0 = fmaf(c1v, e0v.y, d0);
                d0 = fmaf(c2v, e0v.z, d0); d0 = fmaf(c3v, e0v.w, d0);
                d1 = fmaf(c0v, e1v.x, d1); d1 = fmaf(c1v, e1v.y, d1);
                d1 = fmaf(c2v, e1v.z, d1); d1 = fmaf(c3v, e1v.w, d1);
                d2 = fmaf(c0v, e2v.x, d2); d2 = fmaf(c1v, e2v.y, d2);
                d2 = fmaf(c2v, e2v.z, d2); d2 = fmaf(c3v, e2v.w, d2);
                d3 = fmaf(c0v, e3v.x, d3); d3 = fmaf(c1v, e3v.y, d3);
                d3 = fmaf(c2v, e3v.z, d3); d3 = fmaf(c3v, e3v.w, d3);
            }
            float s0 = lds_e2[cq*4+0] - 2.0f*d0;
            float s1 = lds_e2[cq*4+1] - 2.0f*d1;
            float s2 = lds_e2[cq*4+2] - 2.0f*d2;
            float s3 = lds_e2[cq*4+3] - 2.0f*d3;
            int cb = cbase + cq*4;
            if (s0 < best) { best = s0; bc = cb + 0; }
            if (s1 < best) { best = s1; bc = cb + 1; }
            if (s2 < best) { best = s2; bc = cb + 2; }
            if (s3 < best) { best = s3; bc = cb + 3; }
        }
        __syncthreads();
    }

    // ---- privatized counts histogram (emb tile region now dead) ----
    {
        float* hist = smem;   // 512 bins
        #pragma unroll
        for (int i = 0; i < 8; ++i) hist[tid + i*64] = 0.0f;
        __syncthreads();
        if (mask) atomicAdd(&hist[bc], 1.0f);
        __syncthreads();
        #pragma unroll
        for (int i = 0; i < 8; ++i) {
            float h = hist[tid + i*64];
            if (h != 0.0f) atomicAdd(&ws[WS_CNT + tid + i*64], h);
        }
    }

    // ---- MLP layer 1 fused with quant_st + e-loss (phase A: k=0..63) ----
    float h1[32];
    #pragma unroll
    for (int j = 0; j < 32; ++j) h1[j] = b1[j];

    float diff2 = 0.0f;
    {
        const float4* eq4 = (const float4*)(emb + bc*EMB_DIM);
        #pragma unroll
        for (int k4 = 0; k4 < 16; ++k4) {
            float4 q4 = eq4[k4];
            float q[4] = {q4.x, q4.y, q4.z, q4.w};
            #pragma unroll
            for (int u = 0; u < 4; ++u) {
                int k = k4*4 + u;
                float d  = q[u] - coarse[k];
                diff2 += d*d;
                float xv = coarse[k] + d;   // quant_st, matches fl(coarse + (q - coarse))
                #pragma unroll
                for (int j = 0; j < 32; ++j) h1[j] = fmaf(xv, W1[k*32 + j], h1[j]);
            }
        }
    }
    float el = mask ? diff2 : 0.0f;
    el = wave_reduce_sum(el);
    if (tid == 0 && el != 0.0f) atomicAdd(&ws[WS_ELOSS], el);

    // ---- phase B: positional encodings streamed into layer 1 ----
    {
        float fx = px*PCC_SC + 32.0f; fx = (fx - floorf(fx))*2.0f - 1.0f;
        float fy = py*PCC_SC + 32.0f; fy = (fy - floorf(fy))*2.0f - 1.0f;
        float fz = pz*PCC_SC + 32.0f; fz = (fz - floorf(fz))*2.0f - 1.0f;
        float fv[3] = {fx, fy, fz};
        float dv[3] = {rx, ry, rz};
        #pragma unroll
        for (int a = 0; a < 3; ++a) {
            #pragma unroll
            for (int f = 0; f < 4; ++f) {
                float angf = fv[a] * (float)(1 << f);
                float angd = dv[a] * (float)(1 << f);
                float sf = sinf(angf), cf = cosf(angf);
                float sd = sinf(angd), cd = cosf(angd);
                int rowS = 64 + a*8 + f;
                int rowC = rowS + 4;
                int rowSD = 88 + a*8 + f;
                int rowCD = rowSD + 4;
                #pragma unroll
                for (int j = 0; j < 32; ++j) {
                    h1[j] = fmaf(sf, W1[rowS*32 + j], h1[j]);
                    h1[j] = fmaf(cf, W1[rowC*32 + j], h1[j]);
                    h1[j] = fmaf(sd, W1[rowSD*32 + j], h1[j]);
                    h1[j] = fmaf(cd, W1[rowCD*32 + j], h1[j]);
                }
            }
        }
    }
    #pragma unroll
    for (int j = 0; j < 32; ++j) h1[j] = fmaxf(h1[j], 0.0f);

    // layer 2: 32 -> 32
    float h2[32];
    #pragma unroll
    for (int j = 0; j < 32; ++j) h2[j] = b2[j];
    #pragma unroll
    for (int k = 0; k < 32; ++k) {
        float hv = h1[k];
        #pragma unroll
        for (int j = 0; j < 32; ++j) h2[j] = fmaf(hv, W2[k*32 + j], h2[j]);
    }
    #pragma unroll
    for (int j = 0; j < 32; ++j) h2[j] = fmaxf(h2[j], 0.0f);

    // layer 3: 32 -> 28
    float shd[28];
    #pragma unroll
    for (int j = 0; j < 28; ++j) shd[j] = b3[j];
    #pragma unroll
    for (int k = 0; k < 32; ++k) {
        float hv = h2[k];
        #pragma unroll
        for (int j = 0; j < 28; ++j) shd[j] = fmaf(hv, W3[k*28 + j], shd[j]);
    }

    const float mf = mask ? 1.0f : 0.0f;
    float sigma = fmaxf(shd[27], 0.0f) * mf;

    float shm_[9];
    #pragma unroll
    for (int j = 0; j < 9; ++j) shm_[j] = ws[WS_SHM + ray*9 + j];

    float rgb[3];
    #pragma unroll
    for (int c = 0; c < 3; ++c) {
        float acc = 0.0f;
        #pragma unroll
        for (int j = 0; j < 9; ++j) acc = fmaf(shm_[j], shd[c*9 + j], acc);
        rgb[c] = fminf(fmaxf(acc*mf + 0.5f, 0.0f), 1.0f);
    }

    if (live) {
        float4 o4; o4.x = rgb[0]; o4.y = rgb[1]; o4.z = rgb[2]; o4.w = sigma;
        ((float4*)(ws + WS_RGBS))[ray*NINT + s] = o4;   // ray-major
    }
}

// ---------- Kernel C: per-ray compositing, one wave per ray ----------
__global__ void composite_kernel(const float* __restrict__ ws, float* __restrict__ out) {
    const int lane = threadIdx.x & 63;
    const int wid  = threadIdx.x >> 6;
    const int r = blockIdx.x * (blockDim.x >> 6) + wid;
    if (r >= NB) return;

    const float tn = ws[WS_TN + r];
    const float4* rs = ((const float4*)(ws + WS_RGBS)) + r*NINT;

    const int s0 = lane * 14;
    float T = 1.0f, c0 = 0.0f, c1 = 0.0f, c2 = 0.0f, dep = 0.0f, wsum = 0.0f;
    #pragma unroll 2
    for (int i = 0; i < 14; ++i) {
        int s = s0 + i;
        if (s < NINT) {
            float4 v = rs[s];
            float alpha = 1.0f - expf(-v.w * STEP_F);
            float w = alpha * T;
            c0 += w * v.x; c1 += w * v.y; c2 += w * v.z;
            dep  += w * (tn + STEP_F * (float)s);
            wsum += w;
            T *= (1.0f - alpha + 1e-10f);
        }
    }

    float inc = T;
    #pragma unroll
    for (int off = 1; off < 64; off <<= 1) {
        float o = __shfl_up(inc, off, 64);
        if (lane >= off) inc *= o;
    }
    float excl = __shfl_up(inc, 1, 64);
    if (lane == 0) excl = 1.0f;

    c0 *= excl; c1 *= excl; c2 *= excl; dep *= excl; wsum *= excl;
    c0 = wave_reduce_sum(c0);
    c1 = wave_reduce_sum(c1);
    c2 = wave_reduce_sum(c2);
    dep = wave_reduce_sum(dep);
    wsum = wave_reduce_sum(wsum);

    if (lane == 0) {
        float bg = 1.0f - wsum;
        out[r*3+0] = c0 + bg;
        out[r*3+1] = c1 + bg;
        out[r*3+2] = c2 + bg;
        out[768 + r] = dep;
    }
}

// ---------- Kernel D: loss + perplexity ----------
__global__ void finalize_kernel(const float* __restrict__ ws, float* __restrict__ out) {
    __shared__ float red[512];
    int t = threadIdx.x;
    float c = ws[WS_CNT + t];
    red[t] = c;
    __syncthreads();
    #pragma unroll
    for (int off = 256; off > 0; off >>= 1) {
        if (t < off) red[t] += red[t + off];
        __syncthreads();
    }
    float cnt = fmaxf(red[0], 1.0f);
    __syncthreads();
    float avg = c / cnt;
    red[t] = avg * logf(avg + 1e-10f);
    __syncthreads();
    #pragma unroll
    for (int off = 256; off > 0; off >>= 1) {
        if (t < off) red[t] += red[t + off];
        __syncthreads();
    }
    if (t == 0) {
        out[1024] = 0.25f * ws[WS_ELOSS] / (cnt * 64.0f);
        out[1025] = expf(-red[0]);
    }
}

extern "C" void kernel_launch(void* const* d_in, const int* in_sizes, int n_in,
                              void* d_out, int out_size, void* d_ws, size_t ws_size,
                              hipStream_t stream) {
    const float* rays_o = (const float*)d_in[0];
    const float* rays_d = (const float*)d_in[1];
    // d_in[2] = grid_id (int, unused)
    const float* data   = (const float*)d_in[3];
    const float* emb    = (const float*)d_in[4];
    const float* W1 = (const float*)d_in[5];
    const float* b1 = (const float*)d_in[6];
    const float* W2 = (const float*)d_in[7];
    const float* b2 = (const float*)d_in[8];
    const float* W3 = (const float*)d_in[9];
    const float* b3 = (const float*)d_in[10];
    float* ws  = (float*)d_ws;
    float* out = (float*)d_out;

    // zero the atomic accumulators (counts + eloss) every call
    hipMemsetAsync(ws + WS_CNT, 0, (NUM_EMB + 1) * sizeof(float), stream);

    setup_kernel<<<3, 256, 0, stream>>>(rays_o, rays_d, emb, ws);

    dim3 gB((NINT + 63) / 64, NB);   // 14 x 256 blocks, 64 threads each
    point_kernel<<<gB, 64, 0, stream>>>(rays_o, data, emb, W1, b1, W2, b2, W3, b3, ws);

    composite_kernel<<<64, 256, 0, stream>>>(ws, out);
    finalize_kernel<<<1, 512, 0, stream>>>(ws, out);
}